// Round 7
// baseline (182.895 us; speedup 1.0000x reference)
//
#include <hip/hip_runtime.h>

#define NG 32
#define NODES 4096
#define NTOT (NG * NODES)      // 131072
#define DIN 128
#define HID 16
#define ODIM 39
#define NEDGE (NTOT * 32)      // 4194304

typedef unsigned int uint;
typedef unsigned short ushort;

// counting-sort geometry: 16-node segments -> 8192 buckets, payload fits u16
#define NB   8192              // 32 graphs * 256 segments
#define BCAP 768               // mean 512, +11 sigma
#define KHB  256               // blocks in kH/kB2
#define EPB  (NEDGE / KHB)     // 16384 edges per block

// k4 geometry: kk-tile 64 -> 1024 blocks, partial[1024][32][40]
#define K4B  1024
#define PODS 40                // padded ODIM

// ws layout (float offsets unless noted). hist_t overlays agg (dead until kS).
// partial overlays pedge (dead after kS_reg).
#define WS_XL     0            // float[2097152]
#define WS_XR     2097152      // float[2097152]
#define WS_AGG    4194304      // float[2097152]  (uint hist_t[KHB*NB] overlays)
#define WS_CNT    6291456      // float[131072]
#define WS_GCOUNT 6422528      // uint[8192]
#define PEDGE_BYTE_OFF ((size_t)(6422528 + 8192) * 4)          // 25,722,880
#define WS_NEED_FAST (PEDGE_BYTE_OFF + (size_t)NB * BCAP * 2)  // ~36.5 MB
// partial (float[K4B*NG*PODS] = 5.24 MB) lives at PEDGE_BYTE_OFF after kS.

// scan visits blocks XCD-major so each bucket's pedge range is XCD-partitioned
__device__ __forceinline__ int scan_perm(int r) { return ((r & 31) << 3) | (r >> 5); }

// ---------------------------------------------------------------------------
// k1: xl = x @ Wl^T, xr = x @ Wr^T   (fused, one pass over x)
// ---------------------------------------------------------------------------
__global__ __launch_bounds__(256) void k1_lin(const float* __restrict__ x,
                                              const float* __restrict__ Wl,
                                              const float* __restrict__ Wr,
                                              float* __restrict__ xl,
                                              float* __restrict__ xr) {
    __shared__ float xs[64 * 132];
    __shared__ float wls[16 * 132];
    __shared__ float wrs[16 * 132];
    const int t = threadIdx.x;

    #pragma unroll
    for (int i = 0; i < 2; ++i) {
        int f = i * 256 + t;
        int o = f >> 5, k4 = f & 31;
        float4 a = reinterpret_cast<const float4*>(Wl)[f];
        float4 b = reinterpret_cast<const float4*>(Wr)[f];
        *reinterpret_cast<float4*>(&wls[o * 132 + 4 * k4]) = a;
        *reinterpret_cast<float4*>(&wrs[o * 132 + 4 * k4]) = b;
    }

    const long base = (long)blockIdx.x * 64;
    const float4* xg = reinterpret_cast<const float4*>(x) + base * 32;
    #pragma unroll
    for (int i = 0; i < 8; ++i) {
        int f = i * 256 + t;
        int n = f >> 5, k4 = f & 31;
        *reinterpret_cast<float4*>(&xs[n * 132 + 4 * k4]) = xg[f];
    }
    __syncthreads();

    const int o = t & 15, ngrp = t >> 4;
    float accl[4] = {0.f, 0.f, 0.f, 0.f};
    float accr[4] = {0.f, 0.f, 0.f, 0.f};
    for (int k4 = 0; k4 < 32; ++k4) {
        float4 w0 = *reinterpret_cast<const float4*>(&wls[o * 132 + 4 * k4]);
        float4 w1 = *reinterpret_cast<const float4*>(&wrs[o * 132 + 4 * k4]);
        #pragma unroll
        for (int j = 0; j < 4; ++j) {
            float4 xv = *reinterpret_cast<const float4*>(&xs[(ngrp + 16 * j) * 132 + 4 * k4]);
            accl[j] += xv.x * w0.x + xv.y * w0.y + xv.z * w0.z + xv.w * w0.w;
            accr[j] += xv.x * w1.x + xv.y * w1.y + xv.z * w1.z + xv.w * w1.w;
        }
    }
    #pragma unroll
    for (int j = 0; j < 4; ++j) {
        long n = base + ngrp + 16 * j;
        xl[n * HID + o] = accl[j];
        xr[n * HID + o] = accr[j];
    }
}

// ---------------------------------------------------------------------------
// kH: per-block histogram (graph = e&31 = t&31, seg = dst>>4).
//     hist_t[blk][bucket] -> block-exclusive contiguous 32KB write.
// ---------------------------------------------------------------------------
__global__ __launch_bounds__(1024) void kH_hist(const int* __restrict__ ei,
                                                uint* __restrict__ hist_t) {
    __shared__ uint lh[NB];          // 32 KB
    const int t = threadIdx.x;
    const int blk = blockIdx.x;
    for (int i = t; i < NB; i += 1024) lh[i] = 0u;
    __syncthreads();
    const int e0 = blk * EPB;
    #pragma unroll
    for (int j = 0; j < EPB / 1024; ++j) {
        int e = e0 + j * 1024 + t;
        uint dl = (uint)ei[NEDGE + e] & 4095u;
        uint b = (uint)(t & 31) * 256u + (dl >> 4);
        atomicAdd(&lh[b], 1u);
    }
    __syncthreads();
    for (int i = t; i < NB; i += 1024) hist_t[(size_t)blk * NB + i] = lh[i];
}

// ---------------------------------------------------------------------------
// kScan32: per-bucket exclusive scan over the 256 block counts, visiting
// blocks in scan_perm order (XCD-major). Block B owns buckets [B*32, B*32+32).
// ---------------------------------------------------------------------------
__global__ __launch_bounds__(256) void kScan32(uint* __restrict__ hist_t,
                                               uint* __restrict__ gcount) {
    __shared__ uint tile[256 * 33];
    __shared__ uint part[32 * 9];
    const int B = blockIdx.x, t = threadIdx.x;
    const int b0 = B * 32;
    const int cb = t & 31;
    const int rb = t >> 5;

    #pragma unroll
    for (int ch = 0; ch < 32; ++ch) {
        int r = ch * 8 + rb;
        tile[r * 33 + cb] = hist_t[(size_t)scan_perm(r) * NB + b0 + cb];
    }
    __syncthreads();

    const int g2 = t >> 3, l = t & 7;
    {
        uint s = 0u;
        #pragma unroll
        for (int k = 0; k < 32; ++k) s += tile[(l * 32 + k) * 33 + g2];
        part[g2 * 9 + l] = s;
    }
    __syncthreads();
    uint excl = 0u;
    #pragma unroll
    for (int l2 = 0; l2 < 8; ++l2) {
        uint pv = part[g2 * 9 + l2];
        if (l2 < l) excl += pv;
        if (l == 7 && l2 == 7) gcount[b0 + g2] = excl + pv;
    }
    {
        uint run = excl;
        #pragma unroll
        for (int k = 0; k < 32; ++k) {
            uint tmp = tile[(l * 32 + k) * 33 + g2];
            tile[(l * 32 + k) * 33 + g2] = run;
            run += tmp;
        }
    }
    __syncthreads();

    #pragma unroll
    for (int ch = 0; ch < 32; ++ch) {
        int r = ch * 8 + rb;
        hist_t[(size_t)scan_perm(r) * NB + b0 + cb] = tile[r * 33 + cb];
    }
}

// ---------------------------------------------------------------------------
// kB2: second pass; LDS cursors seeded with exact base offsets; u16 scatter.
// ---------------------------------------------------------------------------
__global__ __launch_bounds__(1024) void kB2_place(const int* __restrict__ ei,
                                                  const uint* __restrict__ hist_t,
                                                  ushort* __restrict__ pedge) {
    __shared__ uint lp[NB];          // 32 KB
    const int t = threadIdx.x;
    const int blk = blockIdx.x;
    for (int i = t; i < NB; i += 1024) lp[i] = hist_t[(size_t)blk * NB + i];
    __syncthreads();
    const int e0 = blk * EPB;
    #pragma unroll
    for (int j = 0; j < EPB / 1024; ++j) {
        int e = e0 + j * 1024 + t;
        uint sl = (uint)ei[e] & 4095u;
        uint dl = (uint)ei[NEDGE + e] & 4095u;
        uint b = (uint)(t & 31) * 256u + (dl >> 4);
        uint pos = atomicAdd(&lp[b], 1u);
        if (pos < BCAP)
            pedge[(size_t)b * BCAP + pos] = (ushort)(sl | ((dl & 15u) << 12));
    }
}

// ---------------------------------------------------------------------------
// kS_reg: block per bucket; in-LDS 16-way counting sort, register accumulate.
// ---------------------------------------------------------------------------
__global__ __launch_bounds__(256) void kS_reg(const uint* __restrict__ gcount,
                                              const ushort* __restrict__ pedge,
                                              const float* __restrict__ xl,
                                              float* __restrict__ agg,
                                              float* __restrict__ cnt) {
    __shared__ ushort eb[BCAP];
    __shared__ ushort sorted[BCAP];
    __shared__ uint c16[16];
    __shared__ uint off16[16];
    __shared__ uint cur16[16];
    const int b = blockIdx.x;            // 0..8191
    const int g = b >> 8, seg = b & 255;
    const int t = threadIdx.x;

    if (t < 16) c16[t] = 0u;
    int n = (int)gcount[b];
    if (n > BCAP) n = BCAP;
    const size_t bo = (size_t)b * BCAP;
    for (int i = t; i < n; i += 256) eb[i] = pedge[bo + i];
    __syncthreads();

    for (int i = t; i < n; i += 256) atomicAdd(&c16[eb[i] >> 12], 1u);
    __syncthreads();

    if (t == 0) {
        uint run = 0u;
        #pragma unroll
        for (int d = 0; d < 16; ++d) {
            off16[d] = run;
            cur16[d] = run;
            run += c16[d];
        }
    }
    __syncthreads();

    for (int i = t; i < n; i += 256) {
        ushort p = eb[i];
        uint pos = atomicAdd(&cur16[p >> 12], 1u);
        sorted[pos] = (ushort)(p & 4095u);
    }
    __syncthreads();

    const int dlo = t >> 4, c = t & 15;
    const uint start = off16[dlo];
    const uint len = c16[dlo];
    const float* xrow = xl + (((size_t)g << 12) * HID) + c;
    float acc = 0.f;
    for (uint i = 0; i < len; ++i) {
        int sl = sorted[start + i];          // broadcast across 16-lane group
        acc += xrow[(size_t)sl * HID];       // 64B-row coalesced gather
    }

    agg[(((size_t)g << 12) + (seg << 4)) * HID + t] = acc;
    if (t < 16) cnt[((size_t)g << 12) + (seg << 4) + t] = (float)c16[t];
}

// ---------------------------------------------------------------------------
// k4b: fused h = relu(agg/max(cnt,1) + b_l + xr), skinny GEMM over kk-tile 64.
//      NO atomics: per-block partials -> partial[kb][g][od] (coalesced).
// ---------------------------------------------------------------------------
__global__ __launch_bounds__(256) void k4b_out(const float* __restrict__ agg,
                                               const float* __restrict__ cnt,
                                               const float* __restrict__ xr,
                                               const float* __restrict__ bl,
                                               const float* __restrict__ Wout,
                                               float* __restrict__ partial) {
    __shared__ float hs[32 * 64];      // [g][kk]
    __shared__ float wt[39 * 68];      // [od][kk] pad 64->68
    const int t = threadIdx.x;
    const int kb = blockIdx.x;         // 0..1023
    const int kbase = kb * 64;

    #pragma unroll
    for (int r = 0; r < 8; ++r) {
        int idx = r * 256 + t;         // 0..2047
        int g = idx >> 6, kk = idx & 63;
        long flat = (long)g * (NODES * HID) + kbase + kk;
        float a = agg[flat];
        float xv = xr[flat];
        float cn = cnt[(g << 12) + ((kbase + kk) >> 4)];
        float h = a / fmaxf(cn, 1.0f) + bl[kk & 15] + xv;
        hs[g * 64 + kk] = fmaxf(h, 0.0f);
    }
    for (int idx = t; idx < ODIM * 64; idx += 256) {
        int od = idx >> 6, kk = idx & 63;
        wt[od * 68 + kk] = Wout[(long)od * (NODES * HID) + kbase + kk];
    }
    __syncthreads();

    const int tod = t & 31, tg = t >> 5;
    const int od0 = tod;
    const bool has1 = (tod + 32) < ODIM;
    const int od1 = has1 ? tod + 32 : tod;
    float acc0[4] = {0.f, 0.f, 0.f, 0.f};
    float acc1[4] = {0.f, 0.f, 0.f, 0.f};
    for (int k4 = 0; k4 < 16; ++k4) {
        float4 w0 = *reinterpret_cast<const float4*>(&wt[od0 * 68 + 4 * k4]);
        float4 w1 = *reinterpret_cast<const float4*>(&wt[od1 * 68 + 4 * k4]);
        #pragma unroll
        for (int j = 0; j < 4; ++j) {
            float4 h4 = *reinterpret_cast<const float4*>(&hs[(tg * 4 + j) * 64 + 4 * k4]);
            acc0[j] += h4.x * w0.x + h4.y * w0.y + h4.z * w0.z + h4.w * w0.w;
            acc1[j] += h4.x * w1.x + h4.y * w1.y + h4.z * w1.z + h4.w * w1.w;
        }
    }
    float* pb = partial + (size_t)kb * (NG * PODS);
    #pragma unroll
    for (int j = 0; j < 4; ++j) {
        int g = tg * 4 + j;
        pb[g * PODS + od0] = acc0[j];
        if (has1) pb[g * PODS + od1] = acc1[j];
    }
}

// ---------------------------------------------------------------------------
// kR: out[g][od] = bout[od] + sum_kb partial[kb][g][od]. Block per graph.
// ---------------------------------------------------------------------------
__global__ __launch_bounds__(256) void kR_reduce(const float* __restrict__ partial,
                                                 const float* __restrict__ bout,
                                                 float* __restrict__ out) {
    __shared__ float red[6 * PODS];
    const int g = blockIdx.x, t = threadIdx.x;
    if (t < 240) {
        const int grp = t / PODS, od = t % PODS;
        float acc = 0.f;
        if (od < ODIM) {
            for (int kb = grp; kb < K4B; kb += 6)
                acc += partial[(size_t)kb * (NG * PODS) + g * PODS + od];
        }
        red[grp * PODS + od] = acc;
    }
    __syncthreads();
    if (t < ODIM) {
        float s = bout[t];
        #pragma unroll
        for (int grp = 0; grp < 6; ++grp) s += red[grp * PODS + t];
        out[g * ODIM + t] = s;
    }
}

// ---------------------------------------------------------------------------
// fallback (small ws): global-atomic scatter + atomic k4
// ---------------------------------------------------------------------------
__global__ __launch_bounds__(256) void k2_edges(const int* __restrict__ ei,
                                                const float* __restrict__ xl,
                                                float* __restrict__ agg,
                                                float* __restrict__ cnt) {
    const long tid = (long)blockIdx.x * 256 + threadIdx.x;
    const int e = (int)(tid >> 4);
    const int c = (int)(tid & 15);
    const int s = ei[e];
    const int d = ei[NEDGE + e];
    const float v = xl[(long)s * HID + c];
    atomicAdd(&agg[(long)d * HID + c], v);
    if (c == 0) atomicAdd(&cnt[d], 1.0f);
}

__global__ __launch_bounds__(256) void k3_init_out(const float* __restrict__ bout,
                                                   float* __restrict__ out) {
    int i = blockIdx.x * 256 + threadIdx.x;
    if (i < NG * ODIM) out[i] = bout[i % ODIM];
}

__global__ __launch_bounds__(256) void k4_out(const float* __restrict__ agg,
                                              const float* __restrict__ cnt,
                                              const float* __restrict__ xr,
                                              const float* __restrict__ bl,
                                              const float* __restrict__ Wout,
                                              float* __restrict__ out) {
    __shared__ float hs[32 * 128];
    __shared__ float wt[39 * 132];
    const int t = threadIdx.x;
    const int kbase = blockIdx.x * 128;

    #pragma unroll
    for (int r = 0; r < 16; ++r) {
        int idx = r * 256 + t;
        int g = idx >> 7, kk = idx & 127;
        long flat = (long)g * (NODES * HID) + kbase + kk;
        float a = agg[flat];
        float xv = xr[flat];
        float cn = cnt[(g << 12) + ((kbase + kk) >> 4)];
        float h = a / fmaxf(cn, 1.0f) + bl[kk & 15] + xv;
        hs[g * 128 + kk] = fmaxf(h, 0.0f);
    }
    for (int idx = t; idx < ODIM * 128; idx += 256) {
        int od = idx >> 7, kk = idx & 127;
        wt[od * 132 + kk] = Wout[(long)od * (NODES * HID) + kbase + kk];
    }
    __syncthreads();

    const int tod = t & 31, tg = t >> 5;
    const int od0 = tod;
    const bool has1 = (tod + 32) < ODIM;
    const int od1 = has1 ? tod + 32 : tod;
    float acc0[4] = {0.f, 0.f, 0.f, 0.f};
    float acc1[4] = {0.f, 0.f, 0.f, 0.f};
    for (int k4 = 0; k4 < 32; ++k4) {
        float4 w0 = *reinterpret_cast<const float4*>(&wt[od0 * 132 + 4 * k4]);
        float4 w1 = *reinterpret_cast<const float4*>(&wt[od1 * 132 + 4 * k4]);
        #pragma unroll
        for (int j = 0; j < 4; ++j) {
            float4 h4 = *reinterpret_cast<const float4*>(&hs[(tg * 4 + j) * 128 + 4 * k4]);
            acc0[j] += h4.x * w0.x + h4.y * w0.y + h4.z * w0.z + h4.w * w0.w;
            acc1[j] += h4.x * w1.x + h4.y * w1.y + h4.z * w1.z + h4.w * w1.w;
        }
    }
    #pragma unroll
    for (int j = 0; j < 4; ++j) {
        int g = tg * 4 + j;
        atomicAdd(&out[g * ODIM + od0], acc0[j]);
        if (has1) atomicAdd(&out[g * ODIM + od1], acc1[j]);
    }
}

// ---------------------------------------------------------------------------
extern "C" void kernel_launch(void* const* d_in, const int* in_sizes, int n_in,
                              void* d_out, int out_size, void* d_ws, size_t ws_size,
                              hipStream_t stream) {
    const float* x    = (const float*)d_in[0];
    const int*   ei   = (const int*)d_in[1];
    const float* Wl   = (const float*)d_in[2];
    const float* bl   = (const float*)d_in[3];
    const float* Wr   = (const float*)d_in[4];
    const float* Wout = (const float*)d_in[5];
    const float* bout = (const float*)d_in[6];
    float* out = (float*)d_out;
    float* ws  = (float*)d_ws;

    float* xl  = ws + WS_XL;
    float* xr  = ws + WS_XR;
    float* agg = ws + WS_AGG;
    float* cnt = ws + WS_CNT;

    if (ws_size >= WS_NEED_FAST) {
        uint*   hist_t  = (uint*)(ws + WS_AGG);          // overlays agg
        uint*   gcount  = (uint*)(ws + WS_GCOUNT);
        ushort* pedge   = (ushort*)((char*)d_ws + PEDGE_BYTE_OFF);
        float*  partial = (float*)((char*)d_ws + PEDGE_BYTE_OFF); // after kS

        k1_lin<<<NTOT / 64, 256, 0, stream>>>(x, Wl, Wr, xl, xr);
        kH_hist<<<KHB, 1024, 0, stream>>>(ei, hist_t);
        kScan32<<<NB / 32, 256, 0, stream>>>(hist_t, gcount);
        kB2_place<<<KHB, 1024, 0, stream>>>(ei, hist_t, pedge);
        kS_reg<<<NB, 256, 0, stream>>>(gcount, pedge, xl, agg, cnt);
        k4b_out<<<K4B, 256, 0, stream>>>(agg, cnt, xr, bl, Wout, partial);
        kR_reduce<<<NG, 256, 0, stream>>>(partial, bout, out);
    } else {
        hipMemsetAsync(agg, 0, (size_t)(NTOT * HID + NTOT) * sizeof(float), stream);
        k1_lin<<<NTOT / 64, 256, 0, stream>>>(x, Wl, Wr, xl, xr);
        k2_edges<<<(long)NEDGE * 16 / 256, 256, 0, stream>>>(ei, xl, agg, cnt);
        k3_init_out<<<(NG * ODIM + 255) / 256, 256, 0, stream>>>(bout, out);
        k4_out<<<(NODES * HID) / 128, 256, 0, stream>>>(agg, cnt, xr, bl, Wout, out);
    }
}

// Round 8
// 143.907 us; speedup vs baseline: 1.2709x; 1.2709x over previous
//
#include <hip/hip_runtime.h>

#define NG 32
#define NODES 4096
#define NTOT (NG * NODES)      // 131072
#define DIN 128
#define HID 16
#define ODIM 39
#define NEDGE (NTOT * 32)      // 4194304

typedef unsigned int uint;
typedef unsigned short ushort;

// counting-sort geometry: 16-node segments -> 8192 buckets, payload fits u16
#define NB   8192              // 32 graphs * 256 segments
#define BCAP 768               // mean 512, +11 sigma
#define KHB  256               // blocks in kH/kB2
#define EPB  (NEDGE / KHB)     // 16384 edges per block

// k4 geometry: kk-tile 64 -> 1024 blocks, partial[1024][32][40]
#define K4B  1024
#define PODS 40                // padded ODIM

// ws layout (float offsets unless noted). hist_t overlays agg (dead until kS).
// partial overlays pedge (dead after kS_reg).
#define WS_XL     0            // float[2097152]
#define WS_XR     2097152      // float[2097152]
#define WS_AGG    4194304      // float[2097152]  (uint hist_t[KHB*NB] overlays)
#define WS_CNT    6291456      // float[131072]
#define WS_GCOUNT 6422528      // uint[8192]
#define PEDGE_BYTE_OFF ((size_t)(6422528 + 8192) * 4)          // 25,722,880
#define WS_NEED_FAST (PEDGE_BYTE_OFF + (size_t)NB * BCAP * 2)  // ~36.5 MB
// partial (float[K4B*NG*PODS] = 5.24 MB) lives at PEDGE_BYTE_OFF after kS.

// scan visits blocks XCD-major so each bucket's pedge range is XCD-partitioned
__device__ __forceinline__ int scan_perm(int r) { return ((r & 31) << 3) | (r >> 5); }

// ---------------------------------------------------------------------------
// k1: xl = x @ Wl^T, xr = x @ Wr^T   (fused, one pass over x)
// ---------------------------------------------------------------------------
__global__ __launch_bounds__(256) void k1_lin(const float* __restrict__ x,
                                              const float* __restrict__ Wl,
                                              const float* __restrict__ Wr,
                                              float* __restrict__ xl,
                                              float* __restrict__ xr) {
    __shared__ float xs[64 * 132];
    __shared__ float wls[16 * 132];
    __shared__ float wrs[16 * 132];
    const int t = threadIdx.x;

    #pragma unroll
    for (int i = 0; i < 2; ++i) {
        int f = i * 256 + t;
        int o = f >> 5, k4 = f & 31;
        float4 a = reinterpret_cast<const float4*>(Wl)[f];
        float4 b = reinterpret_cast<const float4*>(Wr)[f];
        *reinterpret_cast<float4*>(&wls[o * 132 + 4 * k4]) = a;
        *reinterpret_cast<float4*>(&wrs[o * 132 + 4 * k4]) = b;
    }

    const long base = (long)blockIdx.x * 64;
    const float4* xg = reinterpret_cast<const float4*>(x) + base * 32;
    #pragma unroll
    for (int i = 0; i < 8; ++i) {
        int f = i * 256 + t;
        int n = f >> 5, k4 = f & 31;
        *reinterpret_cast<float4*>(&xs[n * 132 + 4 * k4]) = xg[f];
    }
    __syncthreads();

    const int o = t & 15, ngrp = t >> 4;
    float accl[4] = {0.f, 0.f, 0.f, 0.f};
    float accr[4] = {0.f, 0.f, 0.f, 0.f};
    for (int k4 = 0; k4 < 32; ++k4) {
        float4 w0 = *reinterpret_cast<const float4*>(&wls[o * 132 + 4 * k4]);
        float4 w1 = *reinterpret_cast<const float4*>(&wrs[o * 132 + 4 * k4]);
        #pragma unroll
        for (int j = 0; j < 4; ++j) {
            float4 xv = *reinterpret_cast<const float4*>(&xs[(ngrp + 16 * j) * 132 + 4 * k4]);
            accl[j] += xv.x * w0.x + xv.y * w0.y + xv.z * w0.z + xv.w * w0.w;
            accr[j] += xv.x * w1.x + xv.y * w1.y + xv.z * w1.z + xv.w * w1.w;
        }
    }
    #pragma unroll
    for (int j = 0; j < 4; ++j) {
        long n = base + ngrp + 16 * j;
        xl[n * HID + o] = accl[j];
        xr[n * HID + o] = accr[j];
    }
}

// ---------------------------------------------------------------------------
// kH: per-block histogram (graph = e&31 = t&31, seg = dst>>4).
// ---------------------------------------------------------------------------
__global__ __launch_bounds__(1024) void kH_hist(const int* __restrict__ ei,
                                                uint* __restrict__ hist_t) {
    __shared__ uint lh[NB];          // 32 KB
    const int t = threadIdx.x;
    const int blk = blockIdx.x;
    for (int i = t; i < NB; i += 1024) lh[i] = 0u;
    __syncthreads();
    const int e0 = blk * EPB;
    #pragma unroll
    for (int j = 0; j < EPB / 1024; ++j) {
        int e = e0 + j * 1024 + t;
        uint dl = (uint)ei[NEDGE + e] & 4095u;
        uint b = (uint)(t & 31) * 256u + (dl >> 4);
        atomicAdd(&lh[b], 1u);
    }
    __syncthreads();
    for (int i = t; i < NB; i += 1024) hist_t[(size_t)blk * NB + i] = lh[i];
}

// ---------------------------------------------------------------------------
// kScan32: per-bucket exclusive scan over the 256 block counts (scan_perm
// order = XCD-major). Block B owns buckets [B*32, B*32+32).
// ---------------------------------------------------------------------------
__global__ __launch_bounds__(256) void kScan32(uint* __restrict__ hist_t,
                                               uint* __restrict__ gcount) {
    __shared__ uint tile[256 * 33];
    __shared__ uint part[32 * 9];
    const int B = blockIdx.x, t = threadIdx.x;
    const int b0 = B * 32;
    const int cb = t & 31;
    const int rb = t >> 5;

    #pragma unroll
    for (int ch = 0; ch < 32; ++ch) {
        int r = ch * 8 + rb;
        tile[r * 33 + cb] = hist_t[(size_t)scan_perm(r) * NB + b0 + cb];
    }
    __syncthreads();

    const int g2 = t >> 3, l = t & 7;
    {
        uint s = 0u;
        #pragma unroll
        for (int k = 0; k < 32; ++k) s += tile[(l * 32 + k) * 33 + g2];
        part[g2 * 9 + l] = s;
    }
    __syncthreads();
    uint excl = 0u;
    #pragma unroll
    for (int l2 = 0; l2 < 8; ++l2) {
        uint pv = part[g2 * 9 + l2];
        if (l2 < l) excl += pv;
        if (l == 7 && l2 == 7) gcount[b0 + g2] = excl + pv;
    }
    {
        uint run = excl;
        #pragma unroll
        for (int k = 0; k < 32; ++k) {
            uint tmp = tile[(l * 32 + k) * 33 + g2];
            tile[(l * 32 + k) * 33 + g2] = run;
            run += tmp;
        }
    }
    __syncthreads();

    #pragma unroll
    for (int ch = 0; ch < 32; ++ch) {
        int r = ch * 8 + rb;
        hist_t[(size_t)scan_perm(r) * NB + b0 + cb] = tile[r * 33 + cb];
    }
}

// ---------------------------------------------------------------------------
// kB2: second pass; LDS cursors seeded with exact base offsets; u16 scatter.
// ---------------------------------------------------------------------------
__global__ __launch_bounds__(1024) void kB2_place(const int* __restrict__ ei,
                                                  const uint* __restrict__ hist_t,
                                                  ushort* __restrict__ pedge) {
    __shared__ uint lp[NB];          // 32 KB
    const int t = threadIdx.x;
    const int blk = blockIdx.x;
    for (int i = t; i < NB; i += 1024) lp[i] = hist_t[(size_t)blk * NB + i];
    __syncthreads();
    const int e0 = blk * EPB;
    #pragma unroll
    for (int j = 0; j < EPB / 1024; ++j) {
        int e = e0 + j * 1024 + t;
        uint sl = (uint)ei[e] & 4095u;
        uint dl = (uint)ei[NEDGE + e] & 4095u;
        uint b = (uint)(t & 31) * 256u + (dl >> 4);
        uint pos = atomicAdd(&lp[b], 1u);
        if (pos < BCAP)
            pedge[(size_t)b * BCAP + pos] = (ushort)(sl | ((dl & 15u) << 12));
    }
}

// ---------------------------------------------------------------------------
// kS_reg: block per bucket; in-LDS 16-way counting sort, register accumulate.
// ---------------------------------------------------------------------------
__global__ __launch_bounds__(256) void kS_reg(const uint* __restrict__ gcount,
                                              const ushort* __restrict__ pedge,
                                              const float* __restrict__ xl,
                                              float* __restrict__ agg,
                                              float* __restrict__ cnt) {
    __shared__ ushort eb[BCAP];
    __shared__ ushort sorted[BCAP];
    __shared__ uint c16[16];
    __shared__ uint off16[16];
    __shared__ uint cur16[16];
    const int b = blockIdx.x;            // 0..8191
    const int g = b >> 8, seg = b & 255;
    const int t = threadIdx.x;

    if (t < 16) c16[t] = 0u;
    int n = (int)gcount[b];
    if (n > BCAP) n = BCAP;
    const size_t bo = (size_t)b * BCAP;
    for (int i = t; i < n; i += 256) eb[i] = pedge[bo + i];
    __syncthreads();

    for (int i = t; i < n; i += 256) atomicAdd(&c16[eb[i] >> 12], 1u);
    __syncthreads();

    if (t == 0) {
        uint run = 0u;
        #pragma unroll
        for (int d = 0; d < 16; ++d) {
            off16[d] = run;
            cur16[d] = run;
            run += c16[d];
        }
    }
    __syncthreads();

    for (int i = t; i < n; i += 256) {
        ushort p = eb[i];
        uint pos = atomicAdd(&cur16[p >> 12], 1u);
        sorted[pos] = (ushort)(p & 4095u);
    }
    __syncthreads();

    const int dlo = t >> 4, c = t & 15;
    const uint start = off16[dlo];
    const uint len = c16[dlo];
    const float* xrow = xl + (((size_t)g << 12) * HID) + c;
    float acc = 0.f;
    for (uint i = 0; i < len; ++i) {
        int sl = sorted[start + i];          // broadcast across 16-lane group
        acc += xrow[(size_t)sl * HID];       // 64B-row coalesced gather
    }

    agg[(((size_t)g << 12) + (seg << 4)) * HID + t] = acc;
    if (t < 16) cnt[((size_t)g << 12) + (seg << 4) + t] = (float)c16[t];
}

// ---------------------------------------------------------------------------
// k4b: fused h = relu(agg/max(cnt,1) + b_l + xr), skinny GEMM over kk-tile 64.
//      NO atomics: per-block partials -> partial[kb][g][od] (coalesced).
// ---------------------------------------------------------------------------
__global__ __launch_bounds__(256) void k4b_out(const float* __restrict__ agg,
                                               const float* __restrict__ cnt,
                                               const float* __restrict__ xr,
                                               const float* __restrict__ bl,
                                               const float* __restrict__ Wout,
                                               float* __restrict__ partial) {
    __shared__ float hs[32 * 64];      // [g][kk]
    __shared__ float wt[39 * 68];      // [od][kk] pad 64->68
    const int t = threadIdx.x;
    const int kb = blockIdx.x;         // 0..1023
    const int kbase = kb * 64;

    #pragma unroll
    for (int r = 0; r < 8; ++r) {
        int idx = r * 256 + t;         // 0..2047
        int g = idx >> 6, kk = idx & 63;
        long flat = (long)g * (NODES * HID) + kbase + kk;
        float a = agg[flat];
        float xv = xr[flat];
        float cn = cnt[(g << 12) + ((kbase + kk) >> 4)];
        float h = a / fmaxf(cn, 1.0f) + bl[kk & 15] + xv;
        hs[g * 64 + kk] = fmaxf(h, 0.0f);
    }
    for (int idx = t; idx < ODIM * 64; idx += 256) {
        int od = idx >> 6, kk = idx & 63;
        wt[od * 68 + kk] = Wout[(long)od * (NODES * HID) + kbase + kk];
    }
    __syncthreads();

    const int tod = t & 31, tg = t >> 5;
    const int od0 = tod;
    const bool has1 = (tod + 32) < ODIM;
    const int od1 = has1 ? tod + 32 : tod;
    float acc0[4] = {0.f, 0.f, 0.f, 0.f};
    float acc1[4] = {0.f, 0.f, 0.f, 0.f};
    for (int k4 = 0; k4 < 16; ++k4) {
        float4 w0 = *reinterpret_cast<const float4*>(&wt[od0 * 68 + 4 * k4]);
        float4 w1 = *reinterpret_cast<const float4*>(&wt[od1 * 68 + 4 * k4]);
        #pragma unroll
        for (int j = 0; j < 4; ++j) {
            float4 h4 = *reinterpret_cast<const float4*>(&hs[(tg * 4 + j) * 64 + 4 * k4]);
            acc0[j] += h4.x * w0.x + h4.y * w0.y + h4.z * w0.z + h4.w * w0.w;
            acc1[j] += h4.x * w1.x + h4.y * w1.y + h4.z * w1.z + h4.w * w1.w;
        }
    }
    float* pb = partial + (size_t)kb * (NG * PODS);
    #pragma unroll
    for (int j = 0; j < 4; ++j) {
        int g = tg * 4 + j;
        pb[g * PODS + od0] = acc0[j];
        if (has1) pb[g * PODS + od1] = acc1[j];
    }
}

// ---------------------------------------------------------------------------
// kR2: parallel tree reduce. Block per (g, od): 256 threads x 4 loads each
//      cover the 1024 kb-partials; shfl + LDS reduce; single store.
// ---------------------------------------------------------------------------
__global__ __launch_bounds__(256) void kR2_reduce(const float* __restrict__ partial,
                                                  const float* __restrict__ bout,
                                                  float* __restrict__ out) {
    const int b = blockIdx.x;            // 0..1279
    const int g = b / PODS, od = b - g * PODS;
    if (od >= ODIM) return;
    const int t = threadIdx.x;
    const float* p = partial + g * PODS + od;
    float acc = 0.f;
    #pragma unroll
    for (int i = 0; i < K4B / 256; ++i)
        acc += p[(size_t)(i * 256 + t) * (NG * PODS)];
    #pragma unroll
    for (int off = 32; off > 0; off >>= 1)
        acc += __shfl_down(acc, off, 64);
    __shared__ float w4[4];
    if ((t & 63) == 0) w4[t >> 6] = acc;
    __syncthreads();
    if (t == 0)
        out[g * ODIM + od] = w4[0] + w4[1] + w4[2] + w4[3] + bout[od];
}

// ---------------------------------------------------------------------------
// fallback (small ws): global-atomic scatter + atomic k4
// ---------------------------------------------------------------------------
__global__ __launch_bounds__(256) void k2_edges(const int* __restrict__ ei,
                                                const float* __restrict__ xl,
                                                float* __restrict__ agg,
                                                float* __restrict__ cnt) {
    const long tid = (long)blockIdx.x * 256 + threadIdx.x;
    const int e = (int)(tid >> 4);
    const int c = (int)(tid & 15);
    const int s = ei[e];
    const int d = ei[NEDGE + e];
    const float v = xl[(long)s * HID + c];
    atomicAdd(&agg[(long)d * HID + c], v);
    if (c == 0) atomicAdd(&cnt[d], 1.0f);
}

__global__ __launch_bounds__(256) void k3_init_out(const float* __restrict__ bout,
                                                   float* __restrict__ out) {
    int i = blockIdx.x * 256 + threadIdx.x;
    if (i < NG * ODIM) out[i] = bout[i % ODIM];
}

__global__ __launch_bounds__(256) void k4_out(const float* __restrict__ agg,
                                              const float* __restrict__ cnt,
                                              const float* __restrict__ xr,
                                              const float* __restrict__ bl,
                                              const float* __restrict__ Wout,
                                              float* __restrict__ out) {
    __shared__ float hs[32 * 128];
    __shared__ float wt[39 * 132];
    const int t = threadIdx.x;
    const int kbase = blockIdx.x * 128;

    #pragma unroll
    for (int r = 0; r < 16; ++r) {
        int idx = r * 256 + t;
        int g = idx >> 7, kk = idx & 127;
        long flat = (long)g * (NODES * HID) + kbase + kk;
        float a = agg[flat];
        float xv = xr[flat];
        float cn = cnt[(g << 12) + ((kbase + kk) >> 4)];
        float h = a / fmaxf(cn, 1.0f) + bl[kk & 15] + xv;
        hs[g * 128 + kk] = fmaxf(h, 0.0f);
    }
    for (int idx = t; idx < ODIM * 128; idx += 256) {
        int od = idx >> 7, kk = idx & 127;
        wt[od * 132 + kk] = Wout[(long)od * (NODES * HID) + kbase + kk];
    }
    __syncthreads();

    const int tod = t & 31, tg = t >> 5;
    const int od0 = tod;
    const bool has1 = (tod + 32) < ODIM;
    const int od1 = has1 ? tod + 32 : tod;
    float acc0[4] = {0.f, 0.f, 0.f, 0.f};
    float acc1[4] = {0.f, 0.f, 0.f, 0.f};
    for (int k4 = 0; k4 < 32; ++k4) {
        float4 w0 = *reinterpret_cast<const float4*>(&wt[od0 * 132 + 4 * k4]);
        float4 w1 = *reinterpret_cast<const float4*>(&wt[od1 * 132 + 4 * k4]);
        #pragma unroll
        for (int j = 0; j < 4; ++j) {
            float4 h4 = *reinterpret_cast<const float4*>(&hs[(tg * 4 + j) * 128 + 4 * k4]);
            acc0[j] += h4.x * w0.x + h4.y * w0.y + h4.z * w0.z + h4.w * w0.w;
            acc1[j] += h4.x * w1.x + h4.y * w1.y + h4.z * w1.z + h4.w * w1.w;
        }
    }
    #pragma unroll
    for (int j = 0; j < 4; ++j) {
        int g = tg * 4 + j;
        atomicAdd(&out[g * ODIM + od0], acc0[j]);
        if (has1) atomicAdd(&out[g * ODIM + od1], acc1[j]);
    }
}

// ---------------------------------------------------------------------------
extern "C" void kernel_launch(void* const* d_in, const int* in_sizes, int n_in,
                              void* d_out, int out_size, void* d_ws, size_t ws_size,
                              hipStream_t stream) {
    const float* x    = (const float*)d_in[0];
    const int*   ei   = (const int*)d_in[1];
    const float* Wl   = (const float*)d_in[2];
    const float* bl   = (const float*)d_in[3];
    const float* Wr   = (const float*)d_in[4];
    const float* Wout = (const float*)d_in[5];
    const float* bout = (const float*)d_in[6];
    float* out = (float*)d_out;
    float* ws  = (float*)d_ws;

    float* xl  = ws + WS_XL;
    float* xr  = ws + WS_XR;
    float* agg = ws + WS_AGG;
    float* cnt = ws + WS_CNT;

    if (ws_size >= WS_NEED_FAST) {
        uint*   hist_t  = (uint*)(ws + WS_AGG);          // overlays agg
        uint*   gcount  = (uint*)(ws + WS_GCOUNT);
        ushort* pedge   = (ushort*)((char*)d_ws + PEDGE_BYTE_OFF);
        float*  partial = (float*)((char*)d_ws + PEDGE_BYTE_OFF); // after kS

        k1_lin<<<NTOT / 64, 256, 0, stream>>>(x, Wl, Wr, xl, xr);
        kH_hist<<<KHB, 1024, 0, stream>>>(ei, hist_t);
        kScan32<<<NB / 32, 256, 0, stream>>>(hist_t, gcount);
        kB2_place<<<KHB, 1024, 0, stream>>>(ei, hist_t, pedge);
        kS_reg<<<NB, 256, 0, stream>>>(gcount, pedge, xl, agg, cnt);
        k4b_out<<<K4B, 256, 0, stream>>>(agg, cnt, xr, bl, Wout, partial);
        kR2_reduce<<<NG * PODS, 256, 0, stream>>>(partial, bout, out);
    } else {
        hipMemsetAsync(agg, 0, (size_t)(NTOT * HID + NTOT) * sizeof(float), stream);
        k1_lin<<<NTOT / 64, 256, 0, stream>>>(x, Wl, Wr, xl, xr);
        k2_edges<<<(long)NEDGE * 16 / 256, 256, 0, stream>>>(ei, xl, agg, cnt);
        k3_init_out<<<(NG * ODIM + 255) / 256, 256, 0, stream>>>(bout, out);
        k4_out<<<(NODES * HID) / 128, 256, 0, stream>>>(agg, cnt, xr, bl, Wout, out);
    }
}

// Round 9
// 129.141 us; speedup vs baseline: 1.4162x; 1.1143x over previous
//
#include <hip/hip_runtime.h>

#define NG 32
#define NODES 4096
#define NTOT (NG * NODES)      // 131072
#define DIN 128
#define HID 16
#define ODIM 39
#define NEDGE (NTOT * 32)      // 4194304

typedef unsigned int uint;
typedef unsigned short ushort;

// counting-sort geometry: 16-node segments -> 8192 buckets, payload fits u16
#define NB   8192              // 32 graphs * 256 segments
#define BCAP 768               // mean 512, +11 sigma
#define KHB  256               // blocks in kH/kB2
#define EPB  (NEDGE / KHB)     // 16384 edges per block

// k4 geometry: kk-tile 64 -> 1024 blocks, partial[1024][32][40]
#define K4B  1024
#define PODS 40                // padded ODIM

// ws layout (float offsets unless noted). hist_t overlays agg (dead until kS).
// partial overlays pedge (dead after kS_reg).
#define WS_XL     0            // float[2097152]
#define WS_XR     2097152      // float[2097152]
#define WS_AGG    4194304      // float[2097152]  (uint hist_t[KHB*NB] overlays)
#define WS_CNT    6291456      // float[131072]
#define WS_GCOUNT 6422528      // uint[8192]
#define PEDGE_BYTE_OFF ((size_t)(6422528 + 8192) * 4)          // 25,722,880
#define WS_NEED_FAST (PEDGE_BYTE_OFF + (size_t)NB * BCAP * 2)  // ~36.5 MB
// partial (float[K4B*NG*PODS] = 5.24 MB) lives at PEDGE_BYTE_OFF after kS.

// scan visits blocks XCD-major so each bucket's pedge range is XCD-partitioned
__device__ __forceinline__ int scan_perm(int r) { return ((r & 31) << 3) | (r >> 5); }

// ---------------------------------------------------------------------------
// k1: xl = x @ Wl^T, xr = x @ Wr^T   (fused, one pass over x)
// ---------------------------------------------------------------------------
__global__ __launch_bounds__(256) void k1_lin(const float* __restrict__ x,
                                              const float* __restrict__ Wl,
                                              const float* __restrict__ Wr,
                                              float* __restrict__ xl,
                                              float* __restrict__ xr) {
    __shared__ float xs[64 * 132];
    __shared__ float wls[16 * 132];
    __shared__ float wrs[16 * 132];
    const int t = threadIdx.x;

    #pragma unroll
    for (int i = 0; i < 2; ++i) {
        int f = i * 256 + t;
        int o = f >> 5, k4 = f & 31;
        float4 a = reinterpret_cast<const float4*>(Wl)[f];
        float4 b = reinterpret_cast<const float4*>(Wr)[f];
        *reinterpret_cast<float4*>(&wls[o * 132 + 4 * k4]) = a;
        *reinterpret_cast<float4*>(&wrs[o * 132 + 4 * k4]) = b;
    }

    const long base = (long)blockIdx.x * 64;
    const float4* xg = reinterpret_cast<const float4*>(x) + base * 32;
    #pragma unroll
    for (int i = 0; i < 8; ++i) {
        int f = i * 256 + t;
        int n = f >> 5, k4 = f & 31;
        *reinterpret_cast<float4*>(&xs[n * 132 + 4 * k4]) = xg[f];
    }
    __syncthreads();

    const int o = t & 15, ngrp = t >> 4;
    float accl[4] = {0.f, 0.f, 0.f, 0.f};
    float accr[4] = {0.f, 0.f, 0.f, 0.f};
    for (int k4 = 0; k4 < 32; ++k4) {
        float4 w0 = *reinterpret_cast<const float4*>(&wls[o * 132 + 4 * k4]);
        float4 w1 = *reinterpret_cast<const float4*>(&wrs[o * 132 + 4 * k4]);
        #pragma unroll
        for (int j = 0; j < 4; ++j) {
            float4 xv = *reinterpret_cast<const float4*>(&xs[(ngrp + 16 * j) * 132 + 4 * k4]);
            accl[j] += xv.x * w0.x + xv.y * w0.y + xv.z * w0.z + xv.w * w0.w;
            accr[j] += xv.x * w1.x + xv.y * w1.y + xv.z * w1.z + xv.w * w1.w;
        }
    }
    #pragma unroll
    for (int j = 0; j < 4; ++j) {
        long n = base + ngrp + 16 * j;
        xl[n * HID + o] = accl[j];
        xr[n * HID + o] = accr[j];
    }
}

// ---------------------------------------------------------------------------
// kH: per-block histogram (graph = e&31 = t&31, seg = dst>>4).
// ---------------------------------------------------------------------------
__global__ __launch_bounds__(1024) void kH_hist(const int* __restrict__ ei,
                                                uint* __restrict__ hist_t) {
    __shared__ uint lh[NB];          // 32 KB
    const int t = threadIdx.x;
    const int blk = blockIdx.x;
    for (int i = t; i < NB; i += 1024) lh[i] = 0u;
    __syncthreads();
    const int e0 = blk * EPB;
    #pragma unroll
    for (int j = 0; j < EPB / 1024; ++j) {
        int e = e0 + j * 1024 + t;
        uint dl = (uint)ei[NEDGE + e] & 4095u;
        uint b = (uint)(t & 31) * 256u + (dl >> 4);
        atomicAdd(&lh[b], 1u);
    }
    __syncthreads();
    for (int i = t; i < NB; i += 1024) hist_t[(size_t)blk * NB + i] = lh[i];
}

// ---------------------------------------------------------------------------
// kScan32: per-bucket exclusive scan over the 256 block counts (scan_perm
// order = XCD-major). Block B owns buckets [B*32, B*32+32).
// ---------------------------------------------------------------------------
__global__ __launch_bounds__(256) void kScan32(uint* __restrict__ hist_t,
                                               uint* __restrict__ gcount) {
    __shared__ uint tile[256 * 33];
    __shared__ uint part[32 * 9];
    const int B = blockIdx.x, t = threadIdx.x;
    const int b0 = B * 32;
    const int cb = t & 31;
    const int rb = t >> 5;

    #pragma unroll
    for (int ch = 0; ch < 32; ++ch) {
        int r = ch * 8 + rb;
        tile[r * 33 + cb] = hist_t[(size_t)scan_perm(r) * NB + b0 + cb];
    }
    __syncthreads();

    const int g2 = t >> 3, l = t & 7;
    {
        uint s = 0u;
        #pragma unroll
        for (int k = 0; k < 32; ++k) s += tile[(l * 32 + k) * 33 + g2];
        part[g2 * 9 + l] = s;
    }
    __syncthreads();
    uint excl = 0u;
    #pragma unroll
    for (int l2 = 0; l2 < 8; ++l2) {
        uint pv = part[g2 * 9 + l2];
        if (l2 < l) excl += pv;
        if (l == 7 && l2 == 7) gcount[b0 + g2] = excl + pv;
    }
    {
        uint run = excl;
        #pragma unroll
        for (int k = 0; k < 32; ++k) {
            uint tmp = tile[(l * 32 + k) * 33 + g2];
            tile[(l * 32 + k) * 33 + g2] = run;
            run += tmp;
        }
    }
    __syncthreads();

    #pragma unroll
    for (int ch = 0; ch < 32; ++ch) {
        int r = ch * 8 + rb;
        hist_t[(size_t)scan_perm(r) * NB + b0 + cb] = tile[r * 33 + cb];
    }
}

// ---------------------------------------------------------------------------
// kB2: second pass; LDS cursors seeded with exact base offsets; int4 edge
//      loads -> 4 independent atomic chains per thread (ILP over DS latency).
// ---------------------------------------------------------------------------
__global__ __launch_bounds__(1024) void kB2_place(const int* __restrict__ ei,
                                                  const uint* __restrict__ hist_t,
                                                  ushort* __restrict__ pedge) {
    __shared__ uint lp[NB];          // 32 KB
    const int t = threadIdx.x;
    const int blk = blockIdx.x;
    for (int i = t; i < NB; i += 1024) lp[i] = hist_t[(size_t)blk * NB + i];
    __syncthreads();
    const int e0 = blk * EPB;
    #pragma unroll
    for (int j = 0; j < EPB / 4096; ++j) {     // 4 iterations, 4 edges each
        int e = e0 + j * 4096 + t * 4;
        int4 s4 = *reinterpret_cast<const int4*>(&ei[e]);
        int4 d4 = *reinterpret_cast<const int4*>(&ei[NEDGE + e]);
        const int sv[4] = {s4.x, s4.y, s4.z, s4.w};
        const int dv[4] = {d4.x, d4.y, d4.z, d4.w};
        #pragma unroll
        for (int q = 0; q < 4; ++q) {
            uint sl = (uint)sv[q] & 4095u;
            uint dl = (uint)dv[q] & 4095u;
            uint b = (uint)((e + q) & 31) * 256u + (dl >> 4);
            uint pos = atomicAdd(&lp[b], 1u);
            if (pos < BCAP)
                pedge[(size_t)b * BCAP + pos] = (ushort)(sl | ((dl & 15u) << 12));
        }
    }
}

// ---------------------------------------------------------------------------
// kS_reg: block per bucket; in-LDS 16-way counting sort, register accumulate.
// ---------------------------------------------------------------------------
__global__ __launch_bounds__(256) void kS_reg(const uint* __restrict__ gcount,
                                              const ushort* __restrict__ pedge,
                                              const float* __restrict__ xl,
                                              float* __restrict__ agg,
                                              float* __restrict__ cnt) {
    __shared__ ushort eb[BCAP];
    __shared__ ushort sorted[BCAP];
    __shared__ uint c16[16];
    __shared__ uint off16[16];
    __shared__ uint cur16[16];
    const int b = blockIdx.x;            // 0..8191
    const int g = b >> 8, seg = b & 255;
    const int t = threadIdx.x;

    if (t < 16) c16[t] = 0u;
    int n = (int)gcount[b];
    if (n > BCAP) n = BCAP;
    const size_t bo = (size_t)b * BCAP;
    for (int i = t; i < n; i += 256) eb[i] = pedge[bo + i];
    __syncthreads();

    for (int i = t; i < n; i += 256) atomicAdd(&c16[eb[i] >> 12], 1u);
    __syncthreads();

    if (t == 0) {
        uint run = 0u;
        #pragma unroll
        for (int d = 0; d < 16; ++d) {
            off16[d] = run;
            cur16[d] = run;
            run += c16[d];
        }
    }
    __syncthreads();

    for (int i = t; i < n; i += 256) {
        ushort p = eb[i];
        uint pos = atomicAdd(&cur16[p >> 12], 1u);
        sorted[pos] = (ushort)(p & 4095u);
    }
    __syncthreads();

    const int dlo = t >> 4, c = t & 15;
    const uint start = off16[dlo];
    const uint len = c16[dlo];
    const float* xrow = xl + (((size_t)g << 12) * HID) + c;
    float acc = 0.f;
    for (uint i = 0; i < len; ++i) {
        int sl = sorted[start + i];          // broadcast across 16-lane group
        acc += xrow[(size_t)sl * HID];       // 64B-row coalesced gather
    }

    agg[(((size_t)g << 12) + (seg << 4)) * HID + t] = acc;
    if (t < 16) cnt[((size_t)g << 12) + (seg << 4) + t] = (float)c16[t];
}

// ---------------------------------------------------------------------------
// k4b: fused h = relu(agg/max(cnt,1) + b_l + xr), skinny GEMM over kk-tile 64.
//      launch_bounds(256,4): cap VGPR ~128 so 4 waves/SIMD (was 204 VGPR/10%).
// ---------------------------------------------------------------------------
__global__ __launch_bounds__(256, 4) void k4b_out(const float* __restrict__ agg,
                                                  const float* __restrict__ cnt,
                                                  const float* __restrict__ xr,
                                                  const float* __restrict__ bl,
                                                  const float* __restrict__ Wout,
                                                  float* __restrict__ partial) {
    __shared__ float hs[32 * 64];      // [g][kk]
    __shared__ float wt[39 * 68];      // [od][kk] pad 64->68
    const int t = threadIdx.x;
    const int kb = blockIdx.x;         // 0..1023
    const int kbase = kb * 64;

    #pragma unroll
    for (int r = 0; r < 8; ++r) {
        int idx = r * 256 + t;         // 0..2047
        int g = idx >> 6, kk = idx & 63;
        long flat = (long)g * (NODES * HID) + kbase + kk;
        float a = agg[flat];
        float xv = xr[flat];
        float cn = cnt[(g << 12) + ((kbase + kk) >> 4)];
        float h = a / fmaxf(cn, 1.0f) + bl[kk & 15] + xv;
        hs[g * 64 + kk] = fmaxf(h, 0.0f);
    }
    for (int idx = t; idx < ODIM * 64; idx += 256) {
        int od = idx >> 6, kk = idx & 63;
        wt[od * 68 + kk] = Wout[(long)od * (NODES * HID) + kbase + kk];
    }
    __syncthreads();

    const int tod = t & 31, tg = t >> 5;
    const int od0 = tod;
    const bool has1 = (tod + 32) < ODIM;
    const int od1 = has1 ? tod + 32 : tod;
    float acc0[4] = {0.f, 0.f, 0.f, 0.f};
    float acc1[4] = {0.f, 0.f, 0.f, 0.f};
    #pragma unroll 4
    for (int k4 = 0; k4 < 16; ++k4) {
        float4 w0 = *reinterpret_cast<const float4*>(&wt[od0 * 68 + 4 * k4]);
        float4 w1 = *reinterpret_cast<const float4*>(&wt[od1 * 68 + 4 * k4]);
        #pragma unroll
        for (int j = 0; j < 4; ++j) {
            float4 h4 = *reinterpret_cast<const float4*>(&hs[(tg * 4 + j) * 64 + 4 * k4]);
            acc0[j] += h4.x * w0.x + h4.y * w0.y + h4.z * w0.z + h4.w * w0.w;
            acc1[j] += h4.x * w1.x + h4.y * w1.y + h4.z * w1.z + h4.w * w1.w;
        }
    }
    float* pb = partial + (size_t)kb * (NG * PODS);
    #pragma unroll
    for (int j = 0; j < 4; ++j) {
        int g = tg * 4 + j;
        pb[g * PODS + od0] = acc0[j];
        if (has1) pb[g * PODS + od1] = acc1[j];
    }
}

// ---------------------------------------------------------------------------
// kR2: parallel tree reduce. Block per (g, od): 256 threads x 4 loads each
//      cover the 1024 kb-partials; shfl + LDS reduce; single store.
// ---------------------------------------------------------------------------
__global__ __launch_bounds__(256) void kR2_reduce(const float* __restrict__ partial,
                                                  const float* __restrict__ bout,
                                                  float* __restrict__ out) {
    const int b = blockIdx.x;            // 0..1279
    const int g = b / PODS, od = b - g * PODS;
    if (od >= ODIM) return;
    const int t = threadIdx.x;
    const float* p = partial + g * PODS + od;
    float acc = 0.f;
    #pragma unroll
    for (int i = 0; i < K4B / 256; ++i)
        acc += p[(size_t)(i * 256 + t) * (NG * PODS)];
    #pragma unroll
    for (int off = 32; off > 0; off >>= 1)
        acc += __shfl_down(acc, off, 64);
    __shared__ float w4[4];
    if ((t & 63) == 0) w4[t >> 6] = acc;
    __syncthreads();
    if (t == 0)
        out[g * ODIM + od] = w4[0] + w4[1] + w4[2] + w4[3] + bout[od];
}

// ---------------------------------------------------------------------------
// fallback (small ws): global-atomic scatter + atomic k4
// ---------------------------------------------------------------------------
__global__ __launch_bounds__(256) void k2_edges(const int* __restrict__ ei,
                                                const float* __restrict__ xl,
                                                float* __restrict__ agg,
                                                float* __restrict__ cnt) {
    const long tid = (long)blockIdx.x * 256 + threadIdx.x;
    const int e = (int)(tid >> 4);
    const int c = (int)(tid & 15);
    const int s = ei[e];
    const int d = ei[NEDGE + e];
    const float v = xl[(long)s * HID + c];
    atomicAdd(&agg[(long)d * HID + c], v);
    if (c == 0) atomicAdd(&cnt[d], 1.0f);
}

__global__ __launch_bounds__(256) void k3_init_out(const float* __restrict__ bout,
                                                   float* __restrict__ out) {
    int i = blockIdx.x * 256 + threadIdx.x;
    if (i < NG * ODIM) out[i] = bout[i % ODIM];
}

__global__ __launch_bounds__(256) void k4_out(const float* __restrict__ agg,
                                              const float* __restrict__ cnt,
                                              const float* __restrict__ xr,
                                              const float* __restrict__ bl,
                                              const float* __restrict__ Wout,
                                              float* __restrict__ out) {
    __shared__ float hs[32 * 128];
    __shared__ float wt[39 * 132];
    const int t = threadIdx.x;
    const int kbase = blockIdx.x * 128;

    #pragma unroll
    for (int r = 0; r < 16; ++r) {
        int idx = r * 256 + t;
        int g = idx >> 7, kk = idx & 127;
        long flat = (long)g * (NODES * HID) + kbase + kk;
        float a = agg[flat];
        float xv = xr[flat];
        float cn = cnt[(g << 12) + ((kbase + kk) >> 4)];
        float h = a / fmaxf(cn, 1.0f) + bl[kk & 15] + xv;
        hs[g * 128 + kk] = fmaxf(h, 0.0f);
    }
    for (int idx = t; idx < ODIM * 128; idx += 256) {
        int od = idx >> 7, kk = idx & 127;
        wt[od * 132 + kk] = Wout[(long)od * (NODES * HID) + kbase + kk];
    }
    __syncthreads();

    const int tod = t & 31, tg = t >> 5;
    const int od0 = tod;
    const bool has1 = (tod + 32) < ODIM;
    const int od1 = has1 ? tod + 32 : tod;
    float acc0[4] = {0.f, 0.f, 0.f, 0.f};
    float acc1[4] = {0.f, 0.f, 0.f, 0.f};
    for (int k4 = 0; k4 < 32; ++k4) {
        float4 w0 = *reinterpret_cast<const float4*>(&wt[od0 * 132 + 4 * k4]);
        float4 w1 = *reinterpret_cast<const float4*>(&wt[od1 * 132 + 4 * k4]);
        #pragma unroll
        for (int j = 0; j < 4; ++j) {
            float4 h4 = *reinterpret_cast<const float4*>(&hs[(tg * 4 + j) * 128 + 4 * k4]);
            acc0[j] += h4.x * w0.x + h4.y * w0.y + h4.z * w0.z + h4.w * w0.w;
            acc1[j] += h4.x * w1.x + h4.y * w1.y + h4.z * w1.z + h4.w * w1.w;
        }
    }
    #pragma unroll
    for (int j = 0; j < 4; ++j) {
        int g = tg * 4 + j;
        atomicAdd(&out[g * ODIM + od0], acc0[j]);
        if (has1) atomicAdd(&out[g * ODIM + od1], acc1[j]);
    }
}

// ---------------------------------------------------------------------------
extern "C" void kernel_launch(void* const* d_in, const int* in_sizes, int n_in,
                              void* d_out, int out_size, void* d_ws, size_t ws_size,
                              hipStream_t stream) {
    const float* x    = (const float*)d_in[0];
    const int*   ei   = (const int*)d_in[1];
    const float* Wl   = (const float*)d_in[2];
    const float* bl   = (const float*)d_in[3];
    const float* Wr   = (const float*)d_in[4];
    const float* Wout = (const float*)d_in[5];
    const float* bout = (const float*)d_in[6];
    float* out = (float*)d_out;
    float* ws  = (float*)d_ws;

    float* xl  = ws + WS_XL;
    float* xr  = ws + WS_XR;
    float* agg = ws + WS_AGG;
    float* cnt = ws + WS_CNT;

    if (ws_size >= WS_NEED_FAST) {
        uint*   hist_t  = (uint*)(ws + WS_AGG);          // overlays agg
        uint*   gcount  = (uint*)(ws + WS_GCOUNT);
        ushort* pedge   = (ushort*)((char*)d_ws + PEDGE_BYTE_OFF);
        float*  partial = (float*)((char*)d_ws + PEDGE_BYTE_OFF); // after kS

        k1_lin<<<NTOT / 64, 256, 0, stream>>>(x, Wl, Wr, xl, xr);
        kH_hist<<<KHB, 1024, 0, stream>>>(ei, hist_t);
        kScan32<<<NB / 32, 256, 0, stream>>>(hist_t, gcount);
        kB2_place<<<KHB, 1024, 0, stream>>>(ei, hist_t, pedge);
        kS_reg<<<NB, 256, 0, stream>>>(gcount, pedge, xl, agg, cnt);
        k4b_out<<<K4B, 256, 0, stream>>>(agg, cnt, xr, bl, Wout, partial);
        kR2_reduce<<<NG * PODS, 256, 0, stream>>>(partial, bout, out);
    } else {
        hipMemsetAsync(agg, 0, (size_t)(NTOT * HID + NTOT) * sizeof(float), stream);
        k1_lin<<<NTOT / 64, 256, 0, stream>>>(x, Wl, Wr, xl, xr);
        k2_edges<<<(long)NEDGE * 16 / 256, 256, 0, stream>>>(ei, xl, agg, cnt);
        k3_init_out<<<(NG * ODIM + 255) / 256, 256, 0, stream>>>(bout, out);
        k4_out<<<(NODES * HID) / 128, 256, 0, stream>>>(agg, cnt, xr, bl, Wout, out);
    }
}